// Round 17
// baseline (1200.055 us; speedup 1.0000x reference)
//
#include <hip/hip_runtime.h>
#include <hip/hip_bf16.h>
#include <math.h>

typedef unsigned short u16;
typedef unsigned long long u64;
typedef __attribute__((ext_vector_type(8))) short short8;
typedef __attribute__((ext_vector_type(4))) float f32x4;
typedef __attribute__((ext_vector_type(2))) _Float16 half2v;

static __device__ __forceinline__ u16 f2b(float x) {
  __hip_bfloat16 h = __float2bfloat16(x);
  return *reinterpret_cast<u16*>(&h);
}
static __device__ __forceinline__ float b2f(u16 u) {
  unsigned int v = ((unsigned int)u) << 16;
  float f;
  __builtin_memcpy(&f, &v, 4);
  return f;
}
static __device__ __forceinline__ u16 f2h(float x) {
  _Float16 h = (_Float16)x;
  u16 u;
  __builtin_memcpy(&u, &h, 2);
  return u;
}
static __device__ __forceinline__ float dot2(unsigned w, unsigned h, float acc) {
  half2v a, b;
  __builtin_memcpy(&a, &w, 4);
  __builtin_memcpy(&b, &h, 4);
#if __has_builtin(__builtin_amdgcn_fdot2)
  return __builtin_amdgcn_fdot2(a, b, acc, false);
#else
  return acc + (float)a[0] * (float)b[0] + (float)a[1] * (float)b[1];
#endif
}

// agent-scope relaxed (cache-bypassing) accessors
static __device__ __forceinline__ float aldf(const float* p) {
  return __hip_atomic_load(const_cast<float*>(p), __ATOMIC_RELAXED, __HIP_MEMORY_SCOPE_AGENT);
}
static __device__ __forceinline__ void astf(float* p, float v) {
  __hip_atomic_store(p, v, __ATOMIC_RELAXED, __HIP_MEMORY_SCOPE_AGENT);
}
static __device__ __forceinline__ u64 ald8(const u64* p) {
  return __hip_atomic_load(const_cast<u64*>(p), __ATOMIC_RELAXED, __HIP_MEMORY_SCOPE_AGENT);
}
static __device__ __forceinline__ void ast32(unsigned* p, unsigned v) {
  __hip_atomic_store(p, v, __ATOMIC_RELAXED, __HIP_MEMORY_SCOPE_AGENT);
}

// ---------------- conversion kernels ----------------

__global__ void cvt_flat(const float* __restrict__ s, u16* __restrict__ d, long n) {
  long i = ((long)blockIdx.x * 256 + threadIdx.x) * 4;
  long stride = (long)gridDim.x * 1024;
  for (; i < n; i += stride) {
    float4 v = *(const float4*)(s + i);
    ushort4 o;
    o.x = f2b(v.x); o.y = f2b(v.y); o.z = f2b(v.z); o.w = f2b(v.w);
    *(ushort4*)(d + i) = o;
  }
}

// pack pairs of f32 -> u32 of 2 f16 (flat)
__global__ void cvt_packh(const float* __restrict__ s, unsigned* __restrict__ d, long npairs) {
  long i = (long)blockIdx.x * 256 + threadIdx.x;
  long step = (long)gridDim.x * 256;
  for (; i < npairs; i += step) {
    float2 v = *(const float2*)(s + 2 * i);
    d[i] = (unsigned)f2h(v.x) | ((unsigned)f2h(v.y) << 16);
  }
}

__global__ void cvt_strided(const float* __restrict__ s, u16* __restrict__ d,
                            long total, int lshift, long sstride, long soff) {
  long i = (long)blockIdx.x * 256 + threadIdx.x;
  long step = (long)gridDim.x * 256;
  long mask = (1L << lshift) - 1;
  for (; i < total; i += step) {
    long r = i >> lshift;
    long c = i & mask;
    d[i] = f2b(s[r * sstride + soff + c]);
  }
}

__global__ void cvt_x(const float* __restrict__ gt, u16* __restrict__ d) {
  long idx = (long)blockIdx.x * 256 + threadIdx.x;
  if (idx >= 1024L * 512) return;
  long m = idx >> 9;
  int k = (int)(idx & 511);
  if (m < 992) {
    int tt = (int)(m >> 5), b = (int)(m & 31);
    d[idx] = f2b(gt[((long)b * 32 + tt) * 512 + k]);
  } else {
    d[idx] = 0;
  }
}

// ---------------- generic MFMA GEMM: C = A(M,K) * B(N,K)^T ----------------
template<int EPI>
__global__ __launch_bounds__(256)
void gemm_bt(const u16* __restrict__ A, const u16* __restrict__ B,
             void* __restrict__ C0,
             const float* __restrict__ bias, const float* __restrict__ pw,
             int M, int N, int K) {
  __shared__ u16 As[4096];
  __shared__ u16 Bs[4096];
  const int tid = threadIdx.x;
  const int lane = tid & 63, wid = tid >> 6;

  int gx = gridDim.x, gy = gridDim.y;
  int orig = blockIdx.y * gx + blockIdx.x;
  int G = gx < 8 ? gx : 8;
  int ng = gx / G;
  int full = ng * G * gy;
  int ct, rt;
  if (orig < full) {
    int grp = orig / (G * gy), rem = orig % (G * gy);
    ct = grp * G + rem % G;
    rt = rem / G;
  } else {
    int Gt = gx - ng * G;
    int rem = orig - full;
    ct = ng * G + rem % Gt;
    rt = rem / Gt;
  }
  const long row0 = (long)rt * 128;
  const long col0 = (long)ct * 128;

  const int wm = (wid >> 1) * 64, wn = (wid & 1) * 64;
  const int fr = lane & 15, fq = lane >> 4;
  const int sr = wid * 16 + (lane >> 2);
  const int sc = (lane & 3) * 8;

  const u16* Ag0 = A + (row0 + sr) * (long)K + sc;
  const u16* Ag1 = Ag0 + 64 * (long)K;
  const u16* Bg0 = B + (col0 + sr) * (long)K + sc;
  const u16* Bg1 = Bg0 + 64 * (long)K;

  u16* AsW0 = &As[wid * 512];
  u16* AsW1 = &As[2048 + wid * 512];
  u16* BsW0 = &Bs[wid * 512];
  u16* BsW1 = &Bs[2048 + wid * 512];

  f32x4 acc[4][4];
#pragma unroll
  for (int i = 0; i < 4; ++i)
#pragma unroll
    for (int j = 0; j < 4; ++j) acc[i][j] = {0.f, 0.f, 0.f, 0.f};

  for (int k0 = 0; k0 < K; k0 += 32) {
    __builtin_amdgcn_global_load_lds((const __attribute__((address_space(1))) void*)(Ag0 + k0),
                                     (__attribute__((address_space(3))) void*)AsW0, 16, 0, 0);
    __builtin_amdgcn_global_load_lds((const __attribute__((address_space(1))) void*)(Ag1 + k0),
                                     (__attribute__((address_space(3))) void*)AsW1, 16, 0, 0);
    __builtin_amdgcn_global_load_lds((const __attribute__((address_space(1))) void*)(Bg0 + k0),
                                     (__attribute__((address_space(3))) void*)BsW0, 16, 0, 0);
    __builtin_amdgcn_global_load_lds((const __attribute__((address_space(1))) void*)(Bg1 + k0),
                                     (__attribute__((address_space(3))) void*)BsW1, 16, 0, 0);
    __syncthreads();
    short8 af[4], bfv[4];
#pragma unroll
    for (int i = 0; i < 4; ++i) af[i] = *(const short8*)&As[(wm + i * 16 + fr) * 32 + fq * 8];
#pragma unroll
    for (int i = 0; i < 4; ++i) bfv[i] = *(const short8*)&Bs[(wn + i * 16 + fr) * 32 + fq * 8];
#pragma unroll
    for (int i = 0; i < 4; ++i)
#pragma unroll
      for (int j = 0; j < 4; ++j)
        acc[i][j] = __builtin_amdgcn_mfma_f32_16x16x32_bf16(af[i], bfv[j], acc[i][j], 0, 0, 0);
    __syncthreads();
  }

#pragma unroll
  for (int i = 0; i < 4; ++i)
#pragma unroll
    for (int j = 0; j < 4; ++j)
#pragma unroll
      for (int q = 0; q < 4; ++q) {
        long gr = row0 + wm + i * 16 + fq * 4 + q;
        long gc = col0 + wn + j * 16 + fr;
        float v = acc[i][j][q];
        if constexpr (EPI == 0) {
          ((u16*)C0)[gr * (long)N + gc] = f2b(v);
        } else if constexpr (EPI == 1) {
          ((u16*)C0)[gr * (long)N + gc] = f2b(tanhf(v + bias[gc]) * pw[gc]);
        } else if constexpr (EPI == 2) {
          if (gr < M) ((float*)C0)[gr * (long)N + gc] = v + bias[gc];
        } else {  // EPI == 3
          if (gr < M) {
            long bb = gr & 31, tt = gr >> 5;
            float o = v + bias[gc];
            __builtin_nontemporal_store(o, &((float*)C0)[(bb * 31 + tt) * (long)N + gc]);
          }
        }
      }
}

// ---------------- persistent recurrence kernel (LDS-pinned weights v3) ----------------
// 256 blocks x 1024 threads, cooperative. = round-15 kernel (best: persist
// 521 us, total 826, FETCH 1.7 MB/step) with ONE change: the gm loop keeps
// FWb row-major (coalesced) but each thread now owns 8 CONSECUTIVE columns
// via short8 row loads: 384 threads x 16 short8 (wave VMEM instrs 768 -> 96,
// still lane-contiguous). r16's transpose lost coalescing (FETCH 5x, persist
// +48%) -- this keeps both properties.
__global__ __launch_bounds__(1024)
void persist(const unsigned* __restrict__ WcatH, const float* __restrict__ bcat,
             const u16* __restrict__ wvfb, const u16* __restrict__ FWb,
             const float* __restrict__ GX, const float* __restrict__ pbv,
             const float* __restrict__ h0,
             unsigned* __restrict__ hG32, float* __restrict__ gates,
             u16* __restrict__ Hbuf, unsigned* __restrict__ cnt) {
  const int tid = threadIdx.x;
  const int blk = blockIdx.x;
  const int rg = blk >> 2, bg = blk & 3;   // phase A role
  const int b = blk >> 3, jc = blk & 7;    // phase B role

  __shared__ unsigned wlds[52 * 516];      // 107.3 KB: pinned f16-packed weights
  __shared__ float hl2[128];               // persistent f32 h slice (b, jc)
  __shared__ __align__(16) char smem[45056];  // phase A/B scratch union
  unsigned* hlds = (unsigned*)smem;            // [8*516] phase A
  float*    plds = (float*)(smem + 16512);     // [416*17] phase A
  float* uhl   = (float*)smem;                 // [256]  phase B
  float* part  = uhl + 256;                    // [1024] phase B
  float* attnv = part + 1024;                  // [128]  phase B
  float* gmp   = attnv + 128;                  // [8*384] phase B (3072 floats)

  const float pb0 = pbv[0];
  if (tid < 128) hl2[tid] = h0[b * 1024 + jc * 128 + tid];

  // preload weight slice: rows [rg*52, +52), 512 u32 each -> wlds stride 516
  for (int it = tid; it < 52 * 512; it += 1024) {
    int row = it >> 9, idx = it & 511;
    wlds[row * 516 + idx] = WcatH[(long)(rg * 52 + row) * 512 + idx];
  }

  auto xbar = [&](unsigned target) {
    __syncthreads();
    if (tid == 0) {
      __hip_atomic_fetch_add(cnt, 1u, __ATOMIC_RELAXED, __HIP_MEMORY_SCOPE_AGENT);
      while (__hip_atomic_load(cnt, __ATOMIC_RELAXED, __HIP_MEMORY_SCOPE_AGENT) < target) {
        __builtin_amdgcn_s_sleep(2);
      }
    }
    __syncthreads();
  };
  xbar(256u);  // weights loaded everywhere; h0/hG32 ready

  for (int t = 0; t < 31; ++t) {
    // ===== phase A: gates GEMV from LDS weights =====
    {
      long base = (long)(bg * 8) * 512;
      int g = tid * 4;
      u64 v0 = ald8((const u64*)(hG32 + base + g));
      u64 v1 = ald8((const u64*)(hG32 + base + g + 2));
      int bi = g >> 9, idx = g & 511;
      unsigned* dst = hlds + bi * 516 + idx;
      dst[0] = (unsigned)v0; dst[1] = (unsigned)(v0 >> 32);
      dst[2] = (unsigned)v1; dst[3] = (unsigned)(v1 >> 32);
    }
    __syncthreads();
    {
      const int akc = tid >> 6, w = tid & 63;
      const int bl = w & 7, rch = w >> 3;
      uint4 hv[8];
      const uint4* hp = (const uint4*)(hlds + bl * 516 + akc * 32);
#pragma unroll
      for (int j = 0; j < 8; ++j) hv[j] = hp[j];
#pragma unroll
      for (int i = 0; i < 7; ++i) {
        int rl = rch * 7 + i;
        if (rl < 52) {
          const uint4* wp = (const uint4*)(wlds + rl * 516 + akc * 32);
          float acc = 0.f;
#pragma unroll
          for (int j = 0; j < 8; ++j) {
            uint4 w4 = wp[j];
            acc = dot2(w4.x, hv[j].x, acc);
            acc = dot2(w4.y, hv[j].y, acc);
            acc = dot2(w4.z, hv[j].z, acc);
            acc = dot2(w4.w, hv[j].w, acc);
          }
          plds[(rl * 8 + bl) * 17 + akc] = acc;
        }
      }
    }
    __syncthreads();
    if (tid < 416) {
      const float* pp = plds + tid * 17;
      float s = 0.f;
#pragma unroll
      for (int k = 0; k < 16; ++k) s += pp[k];
      int rl = tid >> 3, bl = tid & 7;
      astf(gates + (long)(bg * 8 + bl) * 3328 + rg * 52 + rl, s);
    }
    xbar(256u * (2 * t + 2));

    // ===== phase B: attention + GRU =====
    if (tid < 128) {
      u64 v = ald8((const u64*)(gates + (long)b * 3328 + tid * 2));
      float2 f2v;
      __builtin_memcpy(&f2v, &v, 8);
      uhl[tid * 2] = tanhf(f2v.x + bcat[tid * 2]);
      uhl[tid * 2 + 1] = tanhf(f2v.y + bcat[tid * 2 + 1]);
    }
    __syncthreads();
    {
      const int s = tid & 127, q = tid >> 7;  // q in 0..7, 32 dims each
      const u16* wr = wvfb + ((long)(b * 128 + s)) * 256 + q * 32;
      const float* uq = &uhl[q * 32];
      float p = 0.f;
#pragma unroll
      for (int d = 0; d < 32; d += 8) {
        short8 wv = *(const short8*)(wr + d);
#pragma unroll
        for (int e = 0; e < 8; ++e) p += b2f((u16)wv[e]) * uq[d + e];
      }
      part[tid] = p;
    }
    __syncthreads();
    if (tid < 128) {
      float s8 = pb0;
#pragma unroll
      for (int j = 0; j < 8; ++j) s8 += part[tid + 128 * j];
      attnv[tid] = s8;
    }
    __syncthreads();
    if (tid < 64) {
      float m = fmaxf(attnv[tid], attnv[tid + 64]);
#pragma unroll
      for (int o = 32; o; o >>= 1) m = fmaxf(m, __shfl_xor(m, o));
      float e0 = expf(attnv[tid] - m), e1 = expf(attnv[tid + 64] - m);
      float s2 = e0 + e1;
#pragma unroll
      for (int o = 32; o; o >>= 1) s2 += __shfl_xor(s2, o);
      float inv = 1.f / s2;
      attnv[tid] = e0 * inv;
      attnv[tid + 64] = e1 * inv;
    }
    __syncthreads();
    // gm: 384 threads = 3 gates x 16 col-groups x 8 sh; 8 consecutive cols
    // per thread via short8 row loads (coalesced, few instructions).
    if (tid < 384) {
      const int cg = tid % 48, sh = tid / 48;
      const int g = cg >> 4, c8 = (cg & 15) * 8;
      const u16* fw = FWb + ((long)(b * 128 + sh * 16)) * 3072 + g * 1024 + jc * 128 + c8;
      const float* at = &attnv[sh * 16];
      float acc[8] = {0.f, 0.f, 0.f, 0.f, 0.f, 0.f, 0.f, 0.f};
#pragma unroll
      for (int s = 0; s < 16; ++s) {
        short8 v = *(const short8*)(fw + (long)s * 3072);
        float a = at[s];
#pragma unroll
        for (int e = 0; e < 8; ++e) acc[e] += a * b2f((u16)v[e]);
      }
      float* gp = gmp + sh * 384 + g * 128 + c8;
#pragma unroll
      for (int e = 0; e < 8; ++e) gp[e] = acc[e];
    }
    __syncthreads();
    if (tid < 128) {
      const int m = jc * 128 + tid;
      float gm0 = 0.f, gm1 = 0.f, gm2 = 0.f;
#pragma unroll
      for (int s8 = 0; s8 < 8; ++s8) {
        gm0 += gmp[s8 * 384 + tid];
        gm1 += gmp[s8 * 384 + 128 + tid];
        gm2 += gmp[s8 * 384 + 256 + tid];
      }
      float gh0 = aldf(gates + (long)b * 3328 + 256 + m) + bcat[256 + m];
      float gh1 = aldf(gates + (long)b * 3328 + 1280 + m) + bcat[1280 + m];
      float gh2 = aldf(gates + (long)b * 3328 + 2304 + m) + bcat[2304 + m];
      const long gxo = ((long)t * 32 + b) * 3072;
      float xr = GX[gxo + m] + gm0;
      float xz = GX[gxo + 1024 + m] + gm1;
      float xn = GX[gxo + 2048 + m] + gm2;
      float r = 1.f / (1.f + expf(-(xr + gh0)));
      float z = 1.f / (1.f + expf(-(xz + gh1)));
      float n = tanhf(xn + r * gh2);
      float h2 = (1.f - z) * n + z * hl2[tid];
      hl2[tid] = h2;
      Hbuf[((long)t * 32 + b) * 1024 + m] = f2b(h2);
      float hp = __shfl_xor(h2, 1);
      if ((tid & 1) == 0) {
        unsigned pk = (unsigned)f2h(h2) | ((unsigned)f2h(hp) << 16);
        ast32(hG32 + (long)b * 512 + jc * 64 + (tid >> 1), pk);
      }
    }
    xbar(256u * (2 * t + 3));
  }
}

// ---------------- launcher ----------------

extern "C" void kernel_launch(void* const* d_in, const int* in_sizes, int n_in,
                              void* d_out, int out_size, void* d_ws, size_t ws_size,
                              hipStream_t stream) {
  const float* f    = (const float*)d_in[0];
  const float* h0   = (const float*)d_in[1];
  const float* gt   = (const float*)d_in[2];
  const float* U_w  = (const float*)d_in[4];
  const float* U_b  = (const float*)d_in[5];
  const float* V_w  = (const float*)d_in[6];
  const float* V_b  = (const float*)d_in[7];
  const float* P_w  = (const float*)d_in[8];
  const float* P_b  = (const float*)d_in[9];
  const float* W_ih = (const float*)d_in[10];
  const float* b_ih = (const float*)d_in[11];
  const float* W_hh = (const float*)d_in[12];
  const float* b_hh = (const float*)d_in[13];
  const float* dw   = (const float*)d_in[14];
  const float* db   = (const float*)d_in[15];

  char* w = (char*)d_ws;
  auto alloc = [&](size_t bytes) { char* p = w; w += (bytes + 255) & ~255ULL; return p; };

  u16*      fbf   = (u16*)alloc(4096L * 1024 * 2);
  u16*      VwB   = (u16*)alloc(256L * 1024 * 2);
  unsigned* WcatH = (unsigned*)alloc(3328L * 512 * 4);  // f16-packed [U_w; W_hh]
  u16*      WxB   = (u16*)alloc(3072L * 512 * 2);
  u16*      WmB   = (u16*)alloc(3072L * 1024 * 2);
  u16*      dwB   = (u16*)alloc(32000L * 1024 * 2);
  u16*      Xb    = (u16*)alloc(1024L * 512 * 2);
  u16*      wvfb  = (u16*)alloc(4096L * 256 * 2);
  float*    GX    = (float*)alloc(1024L * 3072 * 4);
  u16*      FWb   = (u16*)alloc(4096L * 3072 * 2);
  unsigned* hG32  = (unsigned*)alloc(32L * 512 * 4);    // f16-packed h state
  float*    gates = (float*)alloc(32L * 3328 * 4);
  u16*      Hbuf  = (u16*)alloc(1024L * 1024 * 2);
  float*    bcat  = (float*)alloc(3328L * 4);
  unsigned* cnt   = (unsigned*)alloc(256);

  auto cvg = [](long n) { long g = (n + 1023) / 1024; return (int)(g > 2048 ? 2048 : g); };

  cvt_flat<<<cvg(4194304), 256, 0, stream>>>(f, fbf, 4194304);
  cvt_flat<<<cvg(262144), 256, 0, stream>>>(V_w, VwB, 262144);
  cvt_packh<<<512, 256, 0, stream>>>(U_w, WcatH, 131072);
  cvt_packh<<<2048, 256, 0, stream>>>(W_hh, WcatH + 131072, 1572864);
  cvt_packh<<<64, 256, 0, stream>>>(h0, hG32, 16384);
  cvt_strided<<<2048, 256, 0, stream>>>(W_ih, WxB, 3072L * 512, 9, 1536, 0);
  cvt_strided<<<2048, 256, 0, stream>>>(W_ih, WmB, 3072L * 1024, 10, 1536, 512);
  cvt_flat<<<cvg(32768000), 256, 0, stream>>>(dw, dwB, 32768000);
  cvt_x<<<2048, 256, 0, stream>>>(gt, Xb);
  hipMemcpyAsync(bcat, U_b, 256 * 4, hipMemcpyDeviceToDevice, stream);
  hipMemcpyAsync(bcat + 256, b_hh, 3072 * 4, hipMemcpyDeviceToDevice, stream);
  hipMemsetAsync(cnt, 0, 256, stream);

  // loop-invariant GEMMs (bf16)
  gemm_bt<1><<<dim3(2, 32), 256, 0, stream>>>(fbf, VwB, wvfb, V_b, P_w, 4096, 256, 1024);
  gemm_bt<2><<<dim3(24, 8), 256, 0, stream>>>(Xb, WxB, GX, b_ih, nullptr, 992, 3072, 512);
  gemm_bt<0><<<dim3(24, 32), 256, 0, stream>>>(fbf, WmB, FWb, nullptr, nullptr, 4096, 3072, 1024);

  // full recurrence: persistent kernel, LDS-pinned gate weights + short8 gm
  {
    void* ka[] = {(void*)&WcatH, (void*)&bcat, (void*)&wvfb, (void*)&FWb,
                  (void*)&GX,    (void*)&P_b,  (void*)&h0,   (void*)&hG32,
                  (void*)&gates, (void*)&Hbuf, (void*)&cnt};
    hipLaunchCooperativeKernel((void*)persist, dim3(256), dim3(1024), ka, 0, stream);
  }

  // logits
  gemm_bt<3><<<dim3(250, 8), 256, 0, stream>>>(Hbuf, dwB, (float*)d_out, db, nullptr,
                                               992, 32000, 1024);
}

// Round 18
// 830.457 us; speedup vs baseline: 1.4451x; 1.4451x over previous
//
#include <hip/hip_runtime.h>
#include <hip/hip_bf16.h>
#include <math.h>

typedef unsigned short u16;
typedef unsigned long long u64;
typedef __attribute__((ext_vector_type(8))) short short8;
typedef __attribute__((ext_vector_type(4))) float f32x4;
typedef __attribute__((ext_vector_type(2))) _Float16 half2v;

static __device__ __forceinline__ u16 f2b(float x) {
  __hip_bfloat16 h = __float2bfloat16(x);
  return *reinterpret_cast<u16*>(&h);
}
static __device__ __forceinline__ float b2f(u16 u) {
  unsigned int v = ((unsigned int)u) << 16;
  float f;
  __builtin_memcpy(&f, &v, 4);
  return f;
}
static __device__ __forceinline__ u16 f2h(float x) {
  _Float16 h = (_Float16)x;
  u16 u;
  __builtin_memcpy(&u, &h, 2);
  return u;
}
static __device__ __forceinline__ float dot2(unsigned w, unsigned h, float acc) {
  half2v a, b;
  __builtin_memcpy(&a, &w, 4);
  __builtin_memcpy(&b, &h, 4);
#if __has_builtin(__builtin_amdgcn_fdot2)
  return __builtin_amdgcn_fdot2(a, b, acc, false);
#else
  return acc + (float)a[0] * (float)b[0] + (float)a[1] * (float)b[1];
#endif
}

// agent-scope relaxed (cache-bypassing) accessors
static __device__ __forceinline__ float aldf(const float* p) {
  return __hip_atomic_load(const_cast<float*>(p), __ATOMIC_RELAXED, __HIP_MEMORY_SCOPE_AGENT);
}
static __device__ __forceinline__ void astf(float* p, float v) {
  __hip_atomic_store(p, v, __ATOMIC_RELAXED, __HIP_MEMORY_SCOPE_AGENT);
}
static __device__ __forceinline__ u64 ald8(const u64* p) {
  return __hip_atomic_load(const_cast<u64*>(p), __ATOMIC_RELAXED, __HIP_MEMORY_SCOPE_AGENT);
}
static __device__ __forceinline__ void ast32(unsigned* p, unsigned v) {
  __hip_atomic_store(p, v, __ATOMIC_RELAXED, __HIP_MEMORY_SCOPE_AGENT);
}

// ---------------- conversion kernels ----------------

__global__ void cvt_flat(const float* __restrict__ s, u16* __restrict__ d, long n) {
  long i = ((long)blockIdx.x * 256 + threadIdx.x) * 4;
  long stride = (long)gridDim.x * 1024;
  for (; i < n; i += stride) {
    float4 v = *(const float4*)(s + i);
    ushort4 o;
    o.x = f2b(v.x); o.y = f2b(v.y); o.z = f2b(v.z); o.w = f2b(v.w);
    *(ushort4*)(d + i) = o;
  }
}

// pack pairs of f32 -> u32 of 2 f16 (flat)
__global__ void cvt_packh(const float* __restrict__ s, unsigned* __restrict__ d, long npairs) {
  long i = (long)blockIdx.x * 256 + threadIdx.x;
  long step = (long)gridDim.x * 256;
  for (; i < npairs; i += step) {
    float2 v = *(const float2*)(s + 2 * i);
    d[i] = (unsigned)f2h(v.x) | ((unsigned)f2h(v.y) << 16);
  }
}

__global__ void cvt_strided(const float* __restrict__ s, u16* __restrict__ d,
                            long total, int lshift, long sstride, long soff) {
  long i = (long)blockIdx.x * 256 + threadIdx.x;
  long step = (long)gridDim.x * 256;
  long mask = (1L << lshift) - 1;
  for (; i < total; i += step) {
    long r = i >> lshift;
    long c = i & mask;
    d[i] = f2b(s[r * sstride + soff + c]);
  }
}

__global__ void cvt_x(const float* __restrict__ gt, u16* __restrict__ d) {
  long idx = (long)blockIdx.x * 256 + threadIdx.x;
  if (idx >= 1024L * 512) return;
  long m = idx >> 9;
  int k = (int)(idx & 511);
  if (m < 992) {
    int tt = (int)(m >> 5), b = (int)(m & 31);
    d[idx] = f2b(gt[((long)b * 32 + tt) * 512 + k]);
  } else {
    d[idx] = 0;
  }
}

// ---------------- generic MFMA GEMM: C = A(M,K) * B(N,K)^T ----------------
template<int EPI>
__global__ __launch_bounds__(256)
void gemm_bt(const u16* __restrict__ A, const u16* __restrict__ B,
             void* __restrict__ C0,
             const float* __restrict__ bias, const float* __restrict__ pw,
             int M, int N, int K) {
  __shared__ u16 As[4096];
  __shared__ u16 Bs[4096];
  const int tid = threadIdx.x;
  const int lane = tid & 63, wid = tid >> 6;

  int gx = gridDim.x, gy = gridDim.y;
  int orig = blockIdx.y * gx + blockIdx.x;
  int G = gx < 8 ? gx : 8;
  int ng = gx / G;
  int full = ng * G * gy;
  int ct, rt;
  if (orig < full) {
    int grp = orig / (G * gy), rem = orig % (G * gy);
    ct = grp * G + rem % G;
    rt = rem / G;
  } else {
    int Gt = gx - ng * G;
    int rem = orig - full;
    ct = ng * G + rem % Gt;
    rt = rem / Gt;
  }
  const long row0 = (long)rt * 128;
  const long col0 = (long)ct * 128;

  const int wm = (wid >> 1) * 64, wn = (wid & 1) * 64;
  const int fr = lane & 15, fq = lane >> 4;
  const int sr = wid * 16 + (lane >> 2);
  const int sc = (lane & 3) * 8;

  const u16* Ag0 = A + (row0 + sr) * (long)K + sc;
  const u16* Ag1 = Ag0 + 64 * (long)K;
  const u16* Bg0 = B + (col0 + sr) * (long)K + sc;
  const u16* Bg1 = Bg0 + 64 * (long)K;

  u16* AsW0 = &As[wid * 512];
  u16* AsW1 = &As[2048 + wid * 512];
  u16* BsW0 = &Bs[wid * 512];
  u16* BsW1 = &Bs[2048 + wid * 512];

  f32x4 acc[4][4];
#pragma unroll
  for (int i = 0; i < 4; ++i)
#pragma unroll
    for (int j = 0; j < 4; ++j) acc[i][j] = {0.f, 0.f, 0.f, 0.f};

  for (int k0 = 0; k0 < K; k0 += 32) {
    __builtin_amdgcn_global_load_lds((const __attribute__((address_space(1))) void*)(Ag0 + k0),
                                     (__attribute__((address_space(3))) void*)AsW0, 16, 0, 0);
    __builtin_amdgcn_global_load_lds((const __attribute__((address_space(1))) void*)(Ag1 + k0),
                                     (__attribute__((address_space(3))) void*)AsW1, 16, 0, 0);
    __builtin_amdgcn_global_load_lds((const __attribute__((address_space(1))) void*)(Bg0 + k0),
                                     (__attribute__((address_space(3))) void*)BsW0, 16, 0, 0);
    __builtin_amdgcn_global_load_lds((const __attribute__((address_space(1))) void*)(Bg1 + k0),
                                     (__attribute__((address_space(3))) void*)BsW1, 16, 0, 0);
    __syncthreads();
    short8 af[4], bfv[4];
#pragma unroll
    for (int i = 0; i < 4; ++i) af[i] = *(const short8*)&As[(wm + i * 16 + fr) * 32 + fq * 8];
#pragma unroll
    for (int i = 0; i < 4; ++i) bfv[i] = *(const short8*)&Bs[(wn + i * 16 + fr) * 32 + fq * 8];
#pragma unroll
    for (int i = 0; i < 4; ++i)
#pragma unroll
      for (int j = 0; j < 4; ++j)
        acc[i][j] = __builtin_amdgcn_mfma_f32_16x16x32_bf16(af[i], bfv[j], acc[i][j], 0, 0, 0);
    __syncthreads();
  }

#pragma unroll
  for (int i = 0; i < 4; ++i)
#pragma unroll
    for (int j = 0; j < 4; ++j)
#pragma unroll
      for (int q = 0; q < 4; ++q) {
        long gr = row0 + wm + i * 16 + fq * 4 + q;
        long gc = col0 + wn + j * 16 + fr;
        float v = acc[i][j][q];
        if constexpr (EPI == 0) {
          ((u16*)C0)[gr * (long)N + gc] = f2b(v);
        } else if constexpr (EPI == 1) {
          ((u16*)C0)[gr * (long)N + gc] = f2b(tanhf(v + bias[gc]) * pw[gc]);
        } else if constexpr (EPI == 2) {
          if (gr < M) ((float*)C0)[gr * (long)N + gc] = v + bias[gc];
        } else {  // EPI == 3
          if (gr < M) {
            long bb = gr & 31, tt = gr >> 5;
            float o = v + bias[gc];
            __builtin_nontemporal_store(o, &((float*)C0)[(bb * 31 + tt) * (long)N + gc]);
          }
        }
      }
}

// ---------------- persistent recurrence kernel (r15 + tree barrier) ----------------
// 256 blocks x 1024 threads, cooperative. EXACTLY the round-15 kernel (best
// measured: persist 521 us, total 826, FETCH 1.7 MB/step; phase-B code is
// load-bearing AS WRITTEN -- r16/r17 gm "optimizations" broke FWb cache
// residency and regressed) with ONE change: tree barrier (32 group counters
// 64 B apart + root) replaces the single-counter barrier, cutting per-barrier
// atomic serialization 256 -> max(8, 32).
__global__ __launch_bounds__(1024)
void persist(const unsigned* __restrict__ WcatH, const float* __restrict__ bcat,
             const u16* __restrict__ wvfb, const u16* __restrict__ FWb,
             const float* __restrict__ GX, const float* __restrict__ pbv,
             const float* __restrict__ h0,
             unsigned* __restrict__ hG32, float* __restrict__ gates,
             u16* __restrict__ Hbuf, unsigned* __restrict__ cnt) {
  const int tid = threadIdx.x;
  const int blk = blockIdx.x;
  const int rg = blk >> 2, bg = blk & 3;   // phase A role
  const int b = blk >> 3, jc = blk & 7;    // phase B role

  __shared__ unsigned wlds[52 * 516];      // 107.3 KB: pinned f16-packed weights
  __shared__ float hl2[128];               // persistent f32 h slice (b, jc)
  __shared__ __align__(16) char smem[45056];  // phase A/B scratch union
  unsigned* hlds = (unsigned*)smem;            // [8*516] phase A
  float*    plds = (float*)(smem + 16512);     // [416*17] phase A
  float* uhl   = (float*)smem;                 // [256]  phase B
  float* part  = uhl + 256;                    // [1024] phase B
  float* attnv = part + 1024;                  // [128]  phase B
  float* gmp   = attnv + 128;                  // [3*1024] phase B

  const float pb0 = pbv[0];
  if (tid < 128) hl2[tid] = h0[b * 1024 + jc * 128 + tid];

  // preload weight slice: rows [rg*52, +52), 512 u32 each -> wlds stride 516
  for (int it = tid; it < 52 * 512; it += 1024) {
    int row = it >> 9, idx = it & 511;
    wlds[row * 516 + idx] = WcatH[(long)(rg * 52 + row) * 512 + idx];
  }

  unsigned phctr = 0;
  auto xbar = [&]() {
    ++phctr;
    __syncthreads();
    if (tid == 0) {
      unsigned* gp = cnt + 16 * (blk >> 3);     // 32 groups of 8, 64 B apart
      unsigned* root = cnt + 16 * 32;
      unsigned v = __hip_atomic_fetch_add(gp, 1u, __ATOMIC_RELAXED,
                                          __HIP_MEMORY_SCOPE_AGENT) + 1;
      if (v == 8u * phctr)
        __hip_atomic_fetch_add(root, 1u, __ATOMIC_RELAXED, __HIP_MEMORY_SCOPE_AGENT);
      while (__hip_atomic_load(root, __ATOMIC_RELAXED, __HIP_MEMORY_SCOPE_AGENT) <
             32u * phctr) {
        __builtin_amdgcn_s_sleep(2);
      }
    }
    __syncthreads();
  };
  xbar();  // weights loaded everywhere; h0/hG32 ready

  for (int t = 0; t < 31; ++t) {
    // ===== phase A: gates GEMV from LDS weights =====
    {
      long base = (long)(bg * 8) * 512;
      int g = tid * 4;
      u64 v0 = ald8((const u64*)(hG32 + base + g));
      u64 v1 = ald8((const u64*)(hG32 + base + g + 2));
      int bi = g >> 9, idx = g & 511;
      unsigned* dst = hlds + bi * 516 + idx;
      dst[0] = (unsigned)v0; dst[1] = (unsigned)(v0 >> 32);
      dst[2] = (unsigned)v1; dst[3] = (unsigned)(v1 >> 32);
    }
    __syncthreads();
    {
      const int akc = tid >> 6, w = tid & 63;
      const int bl = w & 7, rch = w >> 3;
      uint4 hv[8];
      const uint4* hp = (const uint4*)(hlds + bl * 516 + akc * 32);
#pragma unroll
      for (int j = 0; j < 8; ++j) hv[j] = hp[j];
#pragma unroll
      for (int i = 0; i < 7; ++i) {
        int rl = rch * 7 + i;
        if (rl < 52) {
          const uint4* wp = (const uint4*)(wlds + rl * 516 + akc * 32);
          float acc = 0.f;
#pragma unroll
          for (int j = 0; j < 8; ++j) {
            uint4 w4 = wp[j];
            acc = dot2(w4.x, hv[j].x, acc);
            acc = dot2(w4.y, hv[j].y, acc);
            acc = dot2(w4.z, hv[j].z, acc);
            acc = dot2(w4.w, hv[j].w, acc);
          }
          plds[(rl * 8 + bl) * 17 + akc] = acc;
        }
      }
    }
    __syncthreads();
    if (tid < 416) {
      const float* pp = plds + tid * 17;
      float s = 0.f;
#pragma unroll
      for (int k = 0; k < 16; ++k) s += pp[k];
      int rl = tid >> 3, bl = tid & 7;
      astf(gates + (long)(bg * 8 + bl) * 3328 + rg * 52 + rl, s);
    }
    xbar();

    // ===== phase B: attention + GRU (r15 verbatim) =====
    if (tid < 128) {
      u64 v = ald8((const u64*)(gates + (long)b * 3328 + tid * 2));
      float2 f2v;
      __builtin_memcpy(&f2v, &v, 8);
      uhl[tid * 2] = tanhf(f2v.x + bcat[tid * 2]);
      uhl[tid * 2 + 1] = tanhf(f2v.y + bcat[tid * 2 + 1]);
    }
    __syncthreads();
    {
      const int s = tid & 127, q = tid >> 7;  // q in 0..7, 32 dims each
      const u16* wr = wvfb + ((long)(b * 128 + s)) * 256 + q * 32;
      const float* uq = &uhl[q * 32];
      float p = 0.f;
#pragma unroll
      for (int d = 0; d < 32; d += 8) {
        short8 wv = *(const short8*)(wr + d);
#pragma unroll
        for (int e = 0; e < 8; ++e) p += b2f((u16)wv[e]) * uq[d + e];
      }
      part[tid] = p;
    }
    __syncthreads();
    if (tid < 128) {
      float s8 = pb0;
#pragma unroll
      for (int j = 0; j < 8; ++j) s8 += part[tid + 128 * j];
      attnv[tid] = s8;
    }
    __syncthreads();
    if (tid < 64) {
      float m = fmaxf(attnv[tid], attnv[tid + 64]);
#pragma unroll
      for (int o = 32; o; o >>= 1) m = fmaxf(m, __shfl_xor(m, o));
      float e0 = expf(attnv[tid] - m), e1 = expf(attnv[tid + 64] - m);
      float s2 = e0 + e1;
#pragma unroll
      for (int o = 32; o; o >>= 1) s2 += __shfl_xor(s2, o);
      float inv = 1.f / s2;
      attnv[tid] = e0 * inv;
      attnv[tid + 64] = e1 * inv;
    }
    __syncthreads();
    {
      const int ml = tid & 127, sh = tid >> 7;  // sh in 0..7, 16 s each
      const int col = jc * 128 + ml;
      float g0 = 0.f, g1 = 0.f, g2 = 0.f;
      const u16* fw = FWb + ((long)(b * 128 + sh * 16)) * 3072 + col;
#pragma unroll 4
      for (int s = 0; s < 16; ++s) {
        float a = attnv[sh * 16 + s];
        g0 += a * b2f(fw[0]);
        g1 += a * b2f(fw[1024]);
        g2 += a * b2f(fw[2048]);
        fw += 3072;
      }
      gmp[0 * 1024 + tid] = g0;
      gmp[1 * 1024 + tid] = g1;
      gmp[2 * 1024 + tid] = g2;
    }
    __syncthreads();
    if (tid < 128) {
      const int m = jc * 128 + tid;
      float gm0 = 0.f, gm1 = 0.f, gm2 = 0.f;
#pragma unroll
      for (int j = 0; j < 8; ++j) {
        gm0 += gmp[0 * 1024 + tid + 128 * j];
        gm1 += gmp[1 * 1024 + tid + 128 * j];
        gm2 += gmp[2 * 1024 + tid + 128 * j];
      }
      float gh0 = aldf(gates + (long)b * 3328 + 256 + m) + bcat[256 + m];
      float gh1 = aldf(gates + (long)b * 3328 + 1280 + m) + bcat[1280 + m];
      float gh2 = aldf(gates + (long)b * 3328 + 2304 + m) + bcat[2304 + m];
      const long gxo = ((long)t * 32 + b) * 3072;
      float xr = GX[gxo + m] + gm0;
      float xz = GX[gxo + 1024 + m] + gm1;
      float xn = GX[gxo + 2048 + m] + gm2;
      float r = 1.f / (1.f + expf(-(xr + gh0)));
      float z = 1.f / (1.f + expf(-(xz + gh1)));
      float n = tanhf(xn + r * gh2);
      float h2 = (1.f - z) * n + z * hl2[tid];
      hl2[tid] = h2;
      Hbuf[((long)t * 32 + b) * 1024 + m] = f2b(h2);
      float hp = __shfl_xor(h2, 1);
      if ((tid & 1) == 0) {
        unsigned pk = (unsigned)f2h(h2) | ((unsigned)f2h(hp) << 16);
        ast32(hG32 + (long)b * 512 + jc * 64 + (tid >> 1), pk);
      }
    }
    xbar();
  }
}

// ---------------- launcher ----------------

extern "C" void kernel_launch(void* const* d_in, const int* in_sizes, int n_in,
                              void* d_out, int out_size, void* d_ws, size_t ws_size,
                              hipStream_t stream) {
  const float* f    = (const float*)d_in[0];
  const float* h0   = (const float*)d_in[1];
  const float* gt   = (const float*)d_in[2];
  const float* U_w  = (const float*)d_in[4];
  const float* U_b  = (const float*)d_in[5];
  const float* V_w  = (const float*)d_in[6];
  const float* V_b  = (const float*)d_in[7];
  const float* P_w  = (const float*)d_in[8];
  const float* P_b  = (const float*)d_in[9];
  const float* W_ih = (const float*)d_in[10];
  const float* b_ih = (const float*)d_in[11];
  const float* W_hh = (const float*)d_in[12];
  const float* b_hh = (const float*)d_in[13];
  const float* dw   = (const float*)d_in[14];
  const float* db   = (const float*)d_in[15];

  char* w = (char*)d_ws;
  auto alloc = [&](size_t bytes) { char* p = w; w += (bytes + 255) & ~255ULL; return p; };

  u16*      fbf   = (u16*)alloc(4096L * 1024 * 2);
  u16*      VwB   = (u16*)alloc(256L * 1024 * 2);
  unsigned* WcatH = (unsigned*)alloc(3328L * 512 * 4);  // f16-packed [U_w; W_hh]
  u16*      WxB   = (u16*)alloc(3072L * 512 * 2);
  u16*      WmB   = (u16*)alloc(3072L * 1024 * 2);
  u16*      dwB   = (u16*)alloc(32000L * 1024 * 2);
  u16*      Xb    = (u16*)alloc(1024L * 512 * 2);
  u16*      wvfb  = (u16*)alloc(4096L * 256 * 2);
  float*    GX    = (float*)alloc(1024L * 3072 * 4);
  u16*      FWb   = (u16*)alloc(4096L * 3072 * 2);
  unsigned* hG32  = (unsigned*)alloc(32L * 512 * 4);    // f16-packed h state
  float*    gates = (float*)alloc(32L * 3328 * 4);
  u16*      Hbuf  = (u16*)alloc(1024L * 1024 * 2);
  float*    bcat  = (float*)alloc(3328L * 4);
  unsigned* cnt   = (unsigned*)alloc(4096);

  auto cvg = [](long n) { long g = (n + 1023) / 1024; return (int)(g > 2048 ? 2048 : g); };

  cvt_flat<<<cvg(4194304), 256, 0, stream>>>(f, fbf, 4194304);
  cvt_flat<<<cvg(262144), 256, 0, stream>>>(V_w, VwB, 262144);
  cvt_packh<<<512, 256, 0, stream>>>(U_w, WcatH, 131072);
  cvt_packh<<<2048, 256, 0, stream>>>(W_hh, WcatH + 131072, 1572864);
  cvt_packh<<<64, 256, 0, stream>>>(h0, hG32, 16384);
  cvt_strided<<<2048, 256, 0, stream>>>(W_ih, WxB, 3072L * 512, 9, 1536, 0);
  cvt_strided<<<2048, 256, 0, stream>>>(W_ih, WmB, 3072L * 1024, 10, 1536, 512);
  cvt_flat<<<cvg(32768000), 256, 0, stream>>>(dw, dwB, 32768000);
  cvt_x<<<2048, 256, 0, stream>>>(gt, Xb);
  hipMemcpyAsync(bcat, U_b, 256 * 4, hipMemcpyDeviceToDevice, stream);
  hipMemcpyAsync(bcat + 256, b_hh, 3072 * 4, hipMemcpyDeviceToDevice, stream);
  hipMemsetAsync(cnt, 0, 4096, stream);

  // loop-invariant GEMMs (bf16)
  gemm_bt<1><<<dim3(2, 32), 256, 0, stream>>>(fbf, VwB, wvfb, V_b, P_w, 4096, 256, 1024);
  gemm_bt<2><<<dim3(24, 8), 256, 0, stream>>>(Xb, WxB, GX, b_ih, nullptr, 992, 3072, 512);
  gemm_bt<0><<<dim3(24, 32), 256, 0, stream>>>(fbf, WmB, FWb, nullptr, nullptr, 4096, 3072, 1024);

  // full recurrence: persistent kernel, LDS-pinned gate weights + tree barrier
  {
    void* ka[] = {(void*)&WcatH, (void*)&bcat, (void*)&wvfb, (void*)&FWb,
                  (void*)&GX,    (void*)&P_b,  (void*)&h0,   (void*)&hG32,
                  (void*)&gates, (void*)&Hbuf, (void*)&cnt};
    hipLaunchCooperativeKernel((void*)persist, dim3(256), dim3(1024), ka, 0, stream);
  }

  // logits
  gemm_bt<3><<<dim3(250, 8), 256, 0, stream>>>(Hbuf, dwB, (float*)d_out, db, nullptr,
                                               992, 32000, 1024);
}

// Round 19
// 798.078 us; speedup vs baseline: 1.5037x; 1.0406x over previous
//
#include <hip/hip_runtime.h>
#include <hip/hip_bf16.h>
#include <math.h>

typedef unsigned short u16;
typedef unsigned long long u64;
typedef __attribute__((ext_vector_type(8))) short short8;
typedef __attribute__((ext_vector_type(4))) float f32x4;
typedef __attribute__((ext_vector_type(2))) _Float16 half2v;

static __device__ __forceinline__ u16 f2b(float x) {
  __hip_bfloat16 h = __float2bfloat16(x);
  return *reinterpret_cast<u16*>(&h);
}
static __device__ __forceinline__ float b2f(u16 u) {
  unsigned int v = ((unsigned int)u) << 16;
  float f;
  __builtin_memcpy(&f, &v, 4);
  return f;
}
static __device__ __forceinline__ u16 f2h(float x) {
  _Float16 h = (_Float16)x;
  u16 u;
  __builtin_memcpy(&u, &h, 2);
  return u;
}
static __device__ __forceinline__ unsigned packh2(float a, float b) {
  return (unsigned)f2h(a) | ((unsigned)f2h(b) << 16);
}
static __device__ __forceinline__ float dot2(unsigned w, unsigned h, float acc) {
  half2v a, b;
  __builtin_memcpy(&a, &w, 4);
  __builtin_memcpy(&b, &h, 4);
#if __has_builtin(__builtin_amdgcn_fdot2)
  return __builtin_amdgcn_fdot2(a, b, acc, false);
#else
  return acc + (float)a[0] * (float)b[0] + (float)a[1] * (float)b[1];
#endif
}

// agent-scope relaxed (cache-bypassing) accessors
static __device__ __forceinline__ float aldf(const float* p) {
  return __hip_atomic_load(const_cast<float*>(p), __ATOMIC_RELAXED, __HIP_MEMORY_SCOPE_AGENT);
}
static __device__ __forceinline__ void astf(float* p, float v) {
  __hip_atomic_store(p, v, __ATOMIC_RELAXED, __HIP_MEMORY_SCOPE_AGENT);
}
static __device__ __forceinline__ u64 ald8(const u64* p) {
  return __hip_atomic_load(const_cast<u64*>(p), __ATOMIC_RELAXED, __HIP_MEMORY_SCOPE_AGENT);
}
static __device__ __forceinline__ void ast32(unsigned* p, unsigned v) {
  __hip_atomic_store(p, v, __ATOMIC_RELAXED, __HIP_MEMORY_SCOPE_AGENT);
}

// ---------------- single consolidated conversion kernel ----------------
// 2048 blocks x 256 threads, statically partitioned; replaces 9 cvt kernels,
// 3 memcpys and the memset (12 fewer dispatch gaps).
__global__ __launch_bounds__(256)
void mega_cvt(const float* __restrict__ f, const float* __restrict__ V_w,
              const float* __restrict__ U_w, const float* __restrict__ W_ih,
              const float* __restrict__ W_hh, const float* __restrict__ dw,
              const float* __restrict__ gt, const float* __restrict__ h0,
              const float* __restrict__ U_b, const float* __restrict__ b_hh,
              u16* __restrict__ fbf, u16* __restrict__ VwB,
              unsigned* __restrict__ WcatH, u16* __restrict__ WxB,
              u16* __restrict__ WmB, u16* __restrict__ dwB,
              u16* __restrict__ Xb, unsigned* __restrict__ hG32,
              float* __restrict__ bcat, unsigned* __restrict__ cnt) {
  const int blk = blockIdx.x, tid = threadIdx.x;
  if (blk < 1600) {  // dw: 8.192M float4 -> ushort4 (dominant segment)
    for (long i = (long)blk * 256 + tid; i < 8192000L; i += 1600L * 256) {
      float4 v = ((const float4*)dw)[i];
      ushort4 o;
      o.x = f2b(v.x); o.y = f2b(v.y); o.z = f2b(v.z); o.w = f2b(v.w);
      ((ushort4*)dwB)[i] = o;
    }
  } else if (blk < 1750) {  // f: 1.048M float4
    for (long i = (long)(blk - 1600) * 256 + tid; i < 1048576L; i += 150L * 256) {
      float4 v = ((const float4*)f)[i];
      ushort4 o;
      o.x = f2b(v.x); o.y = f2b(v.y); o.z = f2b(v.z); o.w = f2b(v.w);
      ((ushort4*)fbf)[i] = o;
    }
  } else if (blk < 1850) {  // WmB = bf16(W_ih[:, 512:1536]), row-major 1024 cols
    for (long i = (long)(blk - 1750) * 256 + tid; i < 3145728L; i += 100L * 256) {
      long r = i >> 10, c = i & 1023;
      WmB[i] = f2b(W_ih[r * 1536 + 512 + c]);
    }
  } else if (blk < 1920) {  // W_hh -> f16-packed WcatH rows 256..3327
    for (long i = (long)(blk - 1850) * 256 + tid; i < 1572864L; i += 70L * 256) {
      float2 v = ((const float2*)W_hh)[i];
      WcatH[131072 + i] = packh2(v.x, v.y);
    }
  } else if (blk < 1980) {  // WxB = bf16(W_ih[:, 0:512])
    for (long i = (long)(blk - 1920) * 256 + tid; i < 1572864L; i += 60L * 256) {
      long r = i >> 9, c = i & 511;
      WxB[i] = f2b(W_ih[r * 1536 + c]);
    }
  } else if (blk < 2000) {  // V_w: 65536 float4
    for (long i = (long)(blk - 1980) * 256 + tid; i < 65536L; i += 20L * 256) {
      float4 v = ((const float4*)V_w)[i];
      ushort4 o;
      o.x = f2b(v.x); o.y = f2b(v.y); o.z = f2b(v.z); o.w = f2b(v.w);
      ((ushort4*)VwB)[i] = o;
    }
  } else if (blk < 2016) {  // U_w -> f16-packed WcatH rows 0..255
    for (long i = (long)(blk - 2000) * 256 + tid; i < 131072L; i += 16L * 256) {
      float2 v = ((const float2*)U_w)[i];
      WcatH[i] = packh2(v.x, v.y);
    }
  } else if (blk < 2040) {  // X: row m = t*32+b <- gt[b, t, :]; rows >= 992 zero
    for (long i = (long)(blk - 2016) * 256 + tid; i < 524288L; i += 24L * 256) {
      long m = i >> 9;
      int k = (int)(i & 511);
      Xb[i] = (m < 992) ? f2b(gt[((m & 31) * 32 + (m >> 5)) * 512 + k]) : (u16)0;
    }
  } else {  // h0 pack + bcat + cnt
    int b0 = blk - 2040;
    for (long i = (long)b0 * 256 + tid; i < 16384L; i += 8L * 256) {
      float2 v = ((const float2*)h0)[i];
      hG32[i] = packh2(v.x, v.y);
    }
    for (int i = b0 * 256 + tid; i < 3328; i += 8 * 256)
      bcat[i] = (i < 256) ? U_b[i] : b_hh[i - 256];
    if (b0 == 0 && tid < 64) cnt[tid] = 0;
  }
}

// ---------------- generic MFMA GEMM: C = A(M,K) * B(N,K)^T ----------------
template<int EPI>
__global__ __launch_bounds__(256)
void gemm_bt(const u16* __restrict__ A, const u16* __restrict__ B,
             void* __restrict__ C0,
             const float* __restrict__ bias, const float* __restrict__ pw,
             int M, int N, int K) {
  __shared__ u16 As[4096];
  __shared__ u16 Bs[4096];
  const int tid = threadIdx.x;
  const int lane = tid & 63, wid = tid >> 6;

  int gx = gridDim.x, gy = gridDim.y;
  int orig = blockIdx.y * gx + blockIdx.x;
  int G = gx < 8 ? gx : 8;
  int ng = gx / G;
  int full = ng * G * gy;
  int ct, rt;
  if (orig < full) {
    int grp = orig / (G * gy), rem = orig % (G * gy);
    ct = grp * G + rem % G;
    rt = rem / G;
  } else {
    int Gt = gx - ng * G;
    int rem = orig - full;
    ct = ng * G + rem % Gt;
    rt = rem / Gt;
  }
  const long row0 = (long)rt * 128;
  const long col0 = (long)ct * 128;

  const int wm = (wid >> 1) * 64, wn = (wid & 1) * 64;
  const int fr = lane & 15, fq = lane >> 4;
  const int sr = wid * 16 + (lane >> 2);
  const int sc = (lane & 3) * 8;

  const u16* Ag0 = A + (row0 + sr) * (long)K + sc;
  const u16* Ag1 = Ag0 + 64 * (long)K;
  const u16* Bg0 = B + (col0 + sr) * (long)K + sc;
  const u16* Bg1 = Bg0 + 64 * (long)K;

  u16* AsW0 = &As[wid * 512];
  u16* AsW1 = &As[2048 + wid * 512];
  u16* BsW0 = &Bs[wid * 512];
  u16* BsW1 = &Bs[2048 + wid * 512];

  f32x4 acc[4][4];
#pragma unroll
  for (int i = 0; i < 4; ++i)
#pragma unroll
    for (int j = 0; j < 4; ++j) acc[i][j] = {0.f, 0.f, 0.f, 0.f};

  for (int k0 = 0; k0 < K; k0 += 32) {
    __builtin_amdgcn_global_load_lds((const __attribute__((address_space(1))) void*)(Ag0 + k0),
                                     (__attribute__((address_space(3))) void*)AsW0, 16, 0, 0);
    __builtin_amdgcn_global_load_lds((const __attribute__((address_space(1))) void*)(Ag1 + k0),
                                     (__attribute__((address_space(3))) void*)AsW1, 16, 0, 0);
    __builtin_amdgcn_global_load_lds((const __attribute__((address_space(1))) void*)(Bg0 + k0),
                                     (__attribute__((address_space(3))) void*)BsW0, 16, 0, 0);
    __builtin_amdgcn_global_load_lds((const __attribute__((address_space(1))) void*)(Bg1 + k0),
                                     (__attribute__((address_space(3))) void*)BsW1, 16, 0, 0);
    __syncthreads();
    short8 af[4], bfv[4];
#pragma unroll
    for (int i = 0; i < 4; ++i) af[i] = *(const short8*)&As[(wm + i * 16 + fr) * 32 + fq * 8];
#pragma unroll
    for (int i = 0; i < 4; ++i) bfv[i] = *(const short8*)&Bs[(wn + i * 16 + fr) * 32 + fq * 8];
#pragma unroll
    for (int i = 0; i < 4; ++i)
#pragma unroll
      for (int j = 0; j < 4; ++j)
        acc[i][j] = __builtin_amdgcn_mfma_f32_16x16x32_bf16(af[i], bfv[j], acc[i][j], 0, 0, 0);
    __syncthreads();
  }

#pragma unroll
  for (int i = 0; i < 4; ++i)
#pragma unroll
    for (int j = 0; j < 4; ++j)
#pragma unroll
      for (int q = 0; q < 4; ++q) {
        long gr = row0 + wm + i * 16 + fq * 4 + q;
        long gc = col0 + wn + j * 16 + fr;
        float v = acc[i][j][q];
        if constexpr (EPI == 0) {
          ((u16*)C0)[gr * (long)N + gc] = f2b(v);
        } else if constexpr (EPI == 1) {
          ((u16*)C0)[gr * (long)N + gc] = f2b(tanhf(v + bias[gc]) * pw[gc]);
        } else if constexpr (EPI == 2) {
          if (gr < M) ((float*)C0)[gr * (long)N + gc] = v + bias[gc];
        } else {  // EPI == 3
          if (gr < M) {
            long bb = gr & 31, tt = gr >> 5;
            float o = v + bias[gc];
            __builtin_nontemporal_store(o, &((float*)C0)[(bb * 31 + tt) * (long)N + gc]);
          }
        }
      }
}

// ---------------- persistent recurrence kernel (r15 verbatim) ----------------
// 256 blocks x 1024 threads, cooperative. Best-measured configuration
// (persist 521 us, FETCH 1.7 MB/step). Phase-B access pattern and the simple
// single-counter barrier are load-bearing AS WRITTEN (r16/r17/r18 lessons).
__global__ __launch_bounds__(1024)
void persist(const unsigned* __restrict__ WcatH, const float* __restrict__ bcat,
             const u16* __restrict__ wvfb, const u16* __restrict__ FWb,
             const float* __restrict__ GX, const float* __restrict__ pbv,
             const float* __restrict__ h0,
             unsigned* __restrict__ hG32, float* __restrict__ gates,
             u16* __restrict__ Hbuf, unsigned* __restrict__ cnt) {
  const int tid = threadIdx.x;
  const int blk = blockIdx.x;
  const int rg = blk >> 2, bg = blk & 3;   // phase A role
  const int b = blk >> 3, jc = blk & 7;    // phase B role

  __shared__ unsigned wlds[52 * 516];      // 107.3 KB: pinned f16-packed weights
  __shared__ float hl2[128];               // persistent f32 h slice (b, jc)
  __shared__ __align__(16) char smem[45056];  // phase A/B scratch union
  unsigned* hlds = (unsigned*)smem;            // [8*516] phase A
  float*    plds = (float*)(smem + 16512);     // [416*17] phase A
  float* uhl   = (float*)smem;                 // [256]  phase B
  float* part  = uhl + 256;                    // [1024] phase B
  float* attnv = part + 1024;                  // [128]  phase B
  float* gmp   = attnv + 128;                  // [3*1024] phase B

  const float pb0 = pbv[0];
  if (tid < 128) hl2[tid] = h0[b * 1024 + jc * 128 + tid];

  // preload weight slice: rows [rg*52, +52), 512 u32 each -> wlds stride 516
  for (int it = tid; it < 52 * 512; it += 1024) {
    int row = it >> 9, idx = it & 511;
    wlds[row * 516 + idx] = WcatH[(long)(rg * 52 + row) * 512 + idx];
  }

  auto xbar = [&](unsigned target) {
    __syncthreads();
    if (tid == 0) {
      __hip_atomic_fetch_add(cnt, 1u, __ATOMIC_RELAXED, __HIP_MEMORY_SCOPE_AGENT);
      while (__hip_atomic_load(cnt, __ATOMIC_RELAXED, __HIP_MEMORY_SCOPE_AGENT) < target) {
        __builtin_amdgcn_s_sleep(2);
      }
    }
    __syncthreads();
  };
  xbar(256u);  // weights loaded everywhere; h0/hG32 ready

  for (int t = 0; t < 31; ++t) {
    // ===== phase A: gates GEMV from LDS weights =====
    {
      long base = (long)(bg * 8) * 512;
      int g = tid * 4;
      u64 v0 = ald8((const u64*)(hG32 + base + g));
      u64 v1 = ald8((const u64*)(hG32 + base + g + 2));
      int bi = g >> 9, idx = g & 511;
      unsigned* dst = hlds + bi * 516 + idx;
      dst[0] = (unsigned)v0; dst[1] = (unsigned)(v0 >> 32);
      dst[2] = (unsigned)v1; dst[3] = (unsigned)(v1 >> 32);
    }
    __syncthreads();
    {
      const int akc = tid >> 6, w = tid & 63;
      const int bl = w & 7, rch = w >> 3;
      uint4 hv[8];
      const uint4* hp = (const uint4*)(hlds + bl * 516 + akc * 32);
#pragma unroll
      for (int j = 0; j < 8; ++j) hv[j] = hp[j];
#pragma unroll
      for (int i = 0; i < 7; ++i) {
        int rl = rch * 7 + i;
        if (rl < 52) {
          const uint4* wp = (const uint4*)(wlds + rl * 516 + akc * 32);
          float acc = 0.f;
#pragma unroll
          for (int j = 0; j < 8; ++j) {
            uint4 w4 = wp[j];
            acc = dot2(w4.x, hv[j].x, acc);
            acc = dot2(w4.y, hv[j].y, acc);
            acc = dot2(w4.z, hv[j].z, acc);
            acc = dot2(w4.w, hv[j].w, acc);
          }
          plds[(rl * 8 + bl) * 17 + akc] = acc;
        }
      }
    }
    __syncthreads();
    if (tid < 416) {
      const float* pp = plds + tid * 17;
      float s = 0.f;
#pragma unroll
      for (int k = 0; k < 16; ++k) s += pp[k];
      int rl = tid >> 3, bl = tid & 7;
      astf(gates + (long)(bg * 8 + bl) * 3328 + rg * 52 + rl, s);
    }
    xbar(256u * (2 * t + 2));

    // ===== phase B: attention + GRU =====
    if (tid < 128) {
      u64 v = ald8((const u64*)(gates + (long)b * 3328 + tid * 2));
      float2 f2v;
      __builtin_memcpy(&f2v, &v, 8);
      uhl[tid * 2] = tanhf(f2v.x + bcat[tid * 2]);
      uhl[tid * 2 + 1] = tanhf(f2v.y + bcat[tid * 2 + 1]);
    }
    __syncthreads();
    {
      const int s = tid & 127, q = tid >> 7;  // q in 0..7, 32 dims each
      const u16* wr = wvfb + ((long)(b * 128 + s)) * 256 + q * 32;
      const float* uq = &uhl[q * 32];
      float p = 0.f;
#pragma unroll
      for (int d = 0; d < 32; d += 8) {
        short8 wv = *(const short8*)(wr + d);
#pragma unroll
        for (int e = 0; e < 8; ++e) p += b2f((u16)wv[e]) * uq[d + e];
      }
      part[tid] = p;
    }
    __syncthreads();
    if (tid < 128) {
      float s8 = pb0;
#pragma unroll
      for (int j = 0; j < 8; ++j) s8 += part[tid + 128 * j];
      attnv[tid] = s8;
    }
    __syncthreads();
    if (tid < 64) {
      float m = fmaxf(attnv[tid], attnv[tid + 64]);
#pragma unroll
      for (int o = 32; o; o >>= 1) m = fmaxf(m, __shfl_xor(m, o));
      float e0 = expf(attnv[tid] - m), e1 = expf(attnv[tid + 64] - m);
      float s2 = e0 + e1;
#pragma unroll
      for (int o = 32; o; o >>= 1) s2 += __shfl_xor(s2, o);
      float inv = 1.f / s2;
      attnv[tid] = e0 * inv;
      attnv[tid + 64] = e1 * inv;
    }
    __syncthreads();
    {
      const int ml = tid & 127, sh = tid >> 7;  // sh in 0..7, 16 s each
      const int col = jc * 128 + ml;
      float g0 = 0.f, g1 = 0.f, g2 = 0.f;
      const u16* fw = FWb + ((long)(b * 128 + sh * 16)) * 3072 + col;
#pragma unroll 4
      for (int s = 0; s < 16; ++s) {
        float a = attnv[sh * 16 + s];
        g0 += a * b2f(fw[0]);
        g1 += a * b2f(fw[1024]);
        g2 += a * b2f(fw[2048]);
        fw += 3072;
      }
      gmp[0 * 1024 + tid] = g0;
      gmp[1 * 1024 + tid] = g1;
      gmp[2 * 1024 + tid] = g2;
    }
    __syncthreads();
    if (tid < 128) {
      const int m = jc * 128 + tid;
      float gm0 = 0.f, gm1 = 0.f, gm2 = 0.f;
#pragma unroll
      for (int j = 0; j < 8; ++j) {
        gm0 += gmp[0 * 1024 + tid + 128 * j];
        gm1 += gmp[1 * 1024 + tid + 128 * j];
        gm2 += gmp[2 * 1024 + tid + 128 * j];
      }
      float gh0 = aldf(gates + (long)b * 3328 + 256 + m) + bcat[256 + m];
      float gh1 = aldf(gates + (long)b * 3328 + 1280 + m) + bcat[1280 + m];
      float gh2 = aldf(gates + (long)b * 3328 + 2304 + m) + bcat[2304 + m];
      const long gxo = ((long)t * 32 + b) * 3072;
      float xr = GX[gxo + m] + gm0;
      float xz = GX[gxo + 1024 + m] + gm1;
      float xn = GX[gxo + 2048 + m] + gm2;
      float r = 1.f / (1.f + expf(-(xr + gh0)));
      float z = 1.f / (1.f + expf(-(xz + gh1)));
      float n = tanhf(xn + r * gh2);
      float h2 = (1.f - z) * n + z * hl2[tid];
      hl2[tid] = h2;
      Hbuf[((long)t * 32 + b) * 1024 + m] = f2b(h2);
      float hp = __shfl_xor(h2, 1);
      if ((tid & 1) == 0) {
        unsigned pk = (unsigned)f2h(h2) | ((unsigned)f2h(hp) << 16);
        ast32(hG32 + (long)b * 512 + jc * 64 + (tid >> 1), pk);
      }
    }
    xbar(256u * (2 * t + 3));
  }
}

// ---------------- launcher ----------------

extern "C" void kernel_launch(void* const* d_in, const int* in_sizes, int n_in,
                              void* d_out, int out_size, void* d_ws, size_t ws_size,
                              hipStream_t stream) {
  const float* f    = (const float*)d_in[0];
  const float* h0   = (const float*)d_in[1];
  const float* gt   = (const float*)d_in[2];
  const float* U_w  = (const float*)d_in[4];
  const float* U_b  = (const float*)d_in[5];
  const float* V_w  = (const float*)d_in[6];
  const float* V_b  = (const float*)d_in[7];
  const float* P_w  = (const float*)d_in[8];
  const float* P_b  = (const float*)d_in[9];
  const float* W_ih = (const float*)d_in[10];
  const float* b_ih = (const float*)d_in[11];
  const float* W_hh = (const float*)d_in[12];
  const float* b_hh = (const float*)d_in[13];
  const float* dw   = (const float*)d_in[14];
  const float* db   = (const float*)d_in[15];

  char* w = (char*)d_ws;
  auto alloc = [&](size_t bytes) { char* p = w; w += (bytes + 255) & ~255ULL; return p; };

  u16*      fbf   = (u16*)alloc(4096L * 1024 * 2);
  u16*      VwB   = (u16*)alloc(256L * 1024 * 2);
  unsigned* WcatH = (unsigned*)alloc(3328L * 512 * 4);  // f16-packed [U_w; W_hh]
  u16*      WxB   = (u16*)alloc(3072L * 512 * 2);
  u16*      WmB   = (u16*)alloc(3072L * 1024 * 2);
  u16*      dwB   = (u16*)alloc(32000L * 1024 * 2);
  u16*      Xb    = (u16*)alloc(1024L * 512 * 2);
  u16*      wvfb  = (u16*)alloc(4096L * 256 * 2);
  float*    GX    = (float*)alloc(1024L * 3072 * 4);
  u16*      FWb   = (u16*)alloc(4096L * 3072 * 2);
  unsigned* hG32  = (unsigned*)alloc(32L * 512 * 4);    // f16-packed h state
  float*    gates = (float*)alloc(32L * 3328 * 4);
  u16*      Hbuf  = (u16*)alloc(1024L * 1024 * 2);
  float*    bcat  = (float*)alloc(3328L * 4);
  unsigned* cnt   = (unsigned*)alloc(256);

  // ONE consolidated conversion kernel (replaces 9 cvts + 3 memcpys + memset)
  mega_cvt<<<2048, 256, 0, stream>>>(f, V_w, U_w, W_ih, W_hh, dw, gt, h0, U_b, b_hh,
                                     fbf, VwB, WcatH, WxB, WmB, dwB, Xb, hG32,
                                     bcat, cnt);

  // loop-invariant GEMMs (bf16)
  gemm_bt<1><<<dim3(2, 32), 256, 0, stream>>>(fbf, VwB, wvfb, V_b, P_w, 4096, 256, 1024);
  gemm_bt<2><<<dim3(24, 8), 256, 0, stream>>>(Xb, WxB, GX, b_ih, nullptr, 992, 3072, 512);
  gemm_bt<0><<<dim3(24, 32), 256, 0, stream>>>(fbf, WmB, FWb, nullptr, nullptr, 4096, 3072, 1024);

  // full recurrence: persistent kernel, LDS-pinned gate weights (r15 config)
  {
    void* ka[] = {(void*)&WcatH, (void*)&bcat, (void*)&wvfb, (void*)&FWb,
                  (void*)&GX,    (void*)&P_b,  (void*)&h0,   (void*)&hG32,
                  (void*)&gates, (void*)&Hbuf, (void*)&cnt};
    hipLaunchCooperativeKernel((void*)persist, dim3(256), dim3(1024), ka, 0, stream);
  }

  // logits
  gemm_bt<3><<<dim3(250, 8), 256, 0, stream>>>(Hbuf, dwB, (float*)d_out, db, nullptr,
                                               992, 32000, 1024);
}